// Round 1
// baseline (1445.862 us; speedup 1.0000x reference)
//
#include <hip/hip_runtime.h>
#include <hip/hip_bf16.h>
#include <stdint.h>

// Problem shape (fixed by setup_inputs): x[2,2048,2048] f32, q[32000,2048] i32,
// absmax[32000,8] f32 -> out[2,2048,32000] f32.  GEMM: M=4096,K=2048,N=32000.
#define M_DIM 4096
#define K_DIM 2048
#define N_DIM 32000
#define V_DIM 32000

typedef __attribute__((ext_vector_type(8))) __bf16 bf16x8;
typedef __attribute__((ext_vector_type(4))) float floatx4;

// ---------------------------------------------------------------------------
// async global->LDS 16B/lane copy (wave-uniform LDS base + lane*16)
// ---------------------------------------------------------------------------
__device__ __forceinline__ void async_copy16(const void* g, void* l) {
    __builtin_amdgcn_global_load_lds(
        (const __attribute__((address_space(1))) void*)(uintptr_t)g,
        (__attribute__((address_space(3))) void*)(uint32_t)(uintptr_t)l,
        16, 0, 0);
}

// ---------------------------------------------------------------------------
// Prepass 1: blockwise dequant int32 codes -> bf16 W  (w = (q-127.5)/127.5*am)
// one thread = 8 contiguous elements (one 16B bf16 store)
// ---------------------------------------------------------------------------
__global__ __launch_bounds__(256) void dequant_w(const int* __restrict__ q,
                                                 const float* __restrict__ absmax,
                                                 __bf16* __restrict__ w) {
    const size_t base = ((size_t)blockIdx.x * 256 + threadIdx.x) * 8;
    const size_t row = base >> 11;            // / K_DIM (2048)
    const int    col = (int)(base & 2047);
    const float  am = absmax[(row << 3) | (col >> 8)];   // 8 qblocks per row
    const float  s  = am * (1.0f / 127.5f);
    const int4* qp = reinterpret_cast<const int4*>(q + base);
    const int4 q0 = qp[0], q1 = qp[1];
    bf16x8 o;
    o[0] = (__bf16)fmaf((float)q0.x, s, -am);
    o[1] = (__bf16)fmaf((float)q0.y, s, -am);
    o[2] = (__bf16)fmaf((float)q0.z, s, -am);
    o[3] = (__bf16)fmaf((float)q0.w, s, -am);
    o[4] = (__bf16)fmaf((float)q1.x, s, -am);
    o[5] = (__bf16)fmaf((float)q1.y, s, -am);
    o[6] = (__bf16)fmaf((float)q1.z, s, -am);
    o[7] = (__bf16)fmaf((float)q1.w, s, -am);
    *reinterpret_cast<bf16x8*>(w + base) = o;
}

// ---------------------------------------------------------------------------
// Prepass 2: x fp32 -> bf16
// ---------------------------------------------------------------------------
__global__ __launch_bounds__(256) void conv_x(const float* __restrict__ x,
                                              __bf16* __restrict__ xb) {
    const size_t base = ((size_t)blockIdx.x * 256 + threadIdx.x) * 8;
    const float4* xp = reinterpret_cast<const float4*>(x + base);
    const float4 a = xp[0], b = xp[1];
    bf16x8 o;
    o[0] = (__bf16)a.x; o[1] = (__bf16)a.y; o[2] = (__bf16)a.z; o[3] = (__bf16)a.w;
    o[4] = (__bf16)b.x; o[5] = (__bf16)b.y; o[6] = (__bf16)b.z; o[7] = (__bf16)b.w;
    *reinterpret_cast<bf16x8*>(xb + base) = o;
}

// ---------------------------------------------------------------------------
// GEMM C[M,N] = A[M,K] * B[N,K]^T   (m97 structure: 128x128 tile, BK=32,
// 4 waves, 4x4 16x16x32 bf16 MFMA per wave, global_load_lds width-16 staging)
// ---------------------------------------------------------------------------
__global__ __launch_bounds__(256) void gemm_bt(const __bf16* __restrict__ A,
                                               const __bf16* __restrict__ Bm,
                                               float* __restrict__ C) {
    __shared__ __bf16 As[128 * 32];   // 8 KB, row-major [row][k], no padding
    __shared__ __bf16 Bs[128 * 32];   // (global_load_lds needs contiguous lanes)

    const int tid  = threadIdx.x;
    const int wave = tid >> 6;
    const int lane = tid & 63;

    const int aRow0 = blockIdx.y * 128;   // M block
    const int bCol0 = blockIdx.x * 128;   // N block

    const int waveM = (wave & 1) * 64;
    const int waveN = (wave >> 1) * 64;
    const int m16  = lane & 15;
    const int quad = lane >> 4;

    // staging: call j covers LDS bytes [j*1024, j*1024+1024) = rows [j*16, j*16+16)
    // lane i -> row j*16 + i/4, k-offset (i%4)*8
    const int j0 = wave * 2, j1 = wave * 2 + 1;
    const int srow = lane >> 2;
    const int skc  = (lane & 3) * 8;

    floatx4 acc[4][4];
#pragma unroll
    for (int i = 0; i < 4; i++)
#pragma unroll
        for (int j = 0; j < 4; j++) acc[i][j] = (floatx4)0.0f;

    for (int k0 = 0; k0 < K_DIM; k0 += 32) {
        async_copy16(A  + (size_t)(aRow0 + j0 * 16 + srow) * K_DIM + k0 + skc, &As[j0 * 512]);
        async_copy16(A  + (size_t)(aRow0 + j1 * 16 + srow) * K_DIM + k0 + skc, &As[j1 * 512]);
        async_copy16(Bm + (size_t)(bCol0 + j0 * 16 + srow) * K_DIM + k0 + skc, &Bs[j0 * 512]);
        async_copy16(Bm + (size_t)(bCol0 + j1 * 16 + srow) * K_DIM + k0 + skc, &Bs[j1 * 512]);
        __syncthreads();   // compiler emits s_waitcnt vmcnt(0) before s_barrier

        bf16x8 a[4], b[4];
#pragma unroll
        for (int mi = 0; mi < 4; mi++)
            a[mi] = *reinterpret_cast<const bf16x8*>(&As[(waveM + mi * 16 + m16) * 32 + quad * 8]);
#pragma unroll
        for (int ni = 0; ni < 4; ni++)
            b[ni] = *reinterpret_cast<const bf16x8*>(&Bs[(waveN + ni * 16 + m16) * 32 + quad * 8]);

#pragma unroll
        for (int mi = 0; mi < 4; mi++)
#pragma unroll
            for (int ni = 0; ni < 4; ni++)
                acc[mi][ni] = __builtin_amdgcn_mfma_f32_16x16x32_bf16(a[mi], b[ni], acc[mi][ni], 0, 0, 0);
        __syncthreads();
    }

    // epilogue: C/D layout col=lane&15, row=quad*4+reg  [verified m89/m91]
#pragma unroll
    for (int mi = 0; mi < 4; mi++) {
#pragma unroll
        for (int ni = 0; ni < 4; ni++) {
            const int grow = aRow0 + waveM + mi * 16 + quad * 4;
            const int gcol = bCol0 + waveN + ni * 16 + m16;
#pragma unroll
            for (int r = 0; r < 4; r++)
                C[(size_t)(grow + r) * N_DIM + gcol] = acc[mi][ni][r];
        }
    }
}

// ---------------------------------------------------------------------------
extern "C" void kernel_launch(void* const* d_in, const int* in_sizes, int n_in,
                              void* d_out, int out_size, void* d_ws, size_t ws_size,
                              hipStream_t stream) {
    const float* x  = (const float*)d_in[0];
    const int*   q  = (const int*)d_in[1];
    const float* am = (const float*)d_in[2];
    float* out = (float*)d_out;

    // workspace layout: W bf16 [V,K] then x bf16 [M,K]
    const size_t w_elems = (size_t)V_DIM * K_DIM;          // 65,536,000
    const size_t x_elems = (size_t)M_DIM * K_DIM;          //  8,388,608
    if (ws_size < (w_elems + x_elems) * sizeof(__bf16)) return;  // ~148 MB needed
    __bf16* wb = (__bf16*)d_ws;
    __bf16* xb = wb + w_elems;

    dequant_w<<<(int)(w_elems / 2048), 256, 0, stream>>>(q, am, wb);
    conv_x<<<(int)(x_elems / 2048), 256, 0, stream>>>(x, xb);

    dim3 grid(N_DIM / 128, M_DIM / 128);   // 250 x 32 = 8000 blocks
    gemm_bt<<<grid, 256, 0, stream>>>(xb, wb, out);
}